// Round 1
// baseline (103.208 us; speedup 1.0000x reference)
//
#include <hip/hip_runtime.h>
#include <math.h>

// GMMflow_fast: B=2048 points, M=1024 components, D=64 dims.
// Factorized form:
//   logw[b,m] = -0.5*( sum_d x^2*a + x*p' ) - 0.5*q[m],  a=1/Sigma, p'=-2*mut*a,
//   q[m] = sum_d (mut^2*a + ln Sigma)
//   u[b,d] = ( x[b,d]*S1[b,d] + S2[b,d] ) / norm[b]
//   S1 = sum_m w*K, S2 = sum_m w*(v - K*mut), norm = sum_m w, w = exp(clip(logw))*Lam
// All f32 vector math (no f32 MFMA on CDNA4; bf16 MFMA too imprecise pre-exp).

#define B_N 2048
#define M_N 1024
#define NSPLIT 16
#define BT 64              // b-tile per block
#define MT 32              // m per LDS tile
#define MS (M_N / NSPLIT)  // 64 m per block
#define PROW 132           // partial row stride (64 S1 + 64 S2 + norm + pad), 528B = 33*16 ok

// ---------------- kernel 1: per-component precompute ----------------
// one 64-lane wave per m; lane = d. 1024 waves -> 256 blocks x 256 thr.
__global__ void precomp_kernel(const float* __restrict__ Mu0, const float* __restrict__ Mu1,
                               const float* __restrict__ S0, const float* __restrict__ S1,
                               const float* __restrict__ T, const float* __restrict__ E,
                               float2* __restrict__ wsAP, float2* __restrict__ wsKG,
                               float* __restrict__ qArr) {
    int gid = blockIdx.x * 256 + threadIdx.x;
    int m = gid >> 6;
    int d = gid & 63;
    float t = T[0], e = E[0];
    float eps2 = e * e;
    float eps4 = eps2 * eps2;
    int idx = m * 64 + d;
    float s0 = S0[idx], s1 = S1[idx];
    float mu0 = Mu0[idx], mu1 = Mu1[idx];
    float Ds = sqrtf(4.f * s0 * s1 + eps4);
    float Cs = 0.5f * (Ds - eps2);
    float omt = 1.f - t;
    float sig = omt * omt * s0 + t * t * s1 + 2.f * t * omt * (Cs + 0.5f * eps2);
    float St = (t * s1 + omt * Cs) - (omt * s0 + t * Cs) - eps2 * t;
    float a = 1.f / sig;
    float K = St * a;
    float mut = omt * mu0 + t * mu1;
    wsAP[idx] = make_float2(a, -2.f * mut * a);          // (a, p' = -2*mut*a)
    wsKG[idx] = make_float2(K, (mu1 - mu0) - K * mut);   // (K, g = v - K*mut)
    float qd = mut * mut * a + logf(sig);
    #pragma unroll
    for (int off = 32; off > 0; off >>= 1) qd += __shfl_xor(qd, off, 64);
    if (d == 0) qArr[m] = qd;
}

// ---------------- kernel 2: transpose X -> XT[d][b] (conflict-free LDS staging later) ----
__global__ void transposeX_kernel(const float* __restrict__ X, float* __restrict__ XT) {
    int gid = blockIdx.x * 256 + threadIdx.x;   // 131072 elems
    int b = gid >> 6, d = gid & 63;
    XT[d * B_N + b] = X[gid];
}

// ---------------- kernel 3: fused main ----------------
// grid (B/BT=32, NSPLIT=16) = 512 blocks, 256 thr, 59KB LDS -> 2 blocks/CU.
__global__ __launch_bounds__(256, 2)
void gmm_main_kernel(const float* __restrict__ Lam,
                     const float2* __restrict__ wsAP, const float2* __restrict__ wsKG,
                     const float* __restrict__ XT, const float* __restrict__ qArr,
                     float* __restrict__ part) {
    // LDS carve-out (floats). All offsets multiple of 4 floats (16B).
    // sAP [64][34] f2 (d-major, +2 pad: b128-aligned reads, spreads transpose-write banks)
    // sKG [32][64] f2 (m-major, direct copy)
    // sX  [64][64] f  (d-major, staged from pre-transposed XT: conflict-free)
    // sW  [32][68] f  (stride 68: 16B-aligned float4 reads, bank-spread writes)
    __shared__ __align__(16) float smem[14784];
    float2* sAP = (float2*)smem;              // 4352 floats
    float2* sKG = (float2*)(smem + 4352);     // 4096 floats
    float*  sX  = smem + 8448;                // 4096 floats
    float*  sW  = smem + 12544;               // 2176 floats
    float*  sQ  = smem + 14720;               // 32
    float*  sL  = smem + 14752;               // 32

    const int tid  = threadIdx.x;
    const int Boff = blockIdx.x * BT;
    const int Moff = blockIdx.y * MS;
    const int mg = tid & 15;   // phase1: m-pair index (2 m's)
    const int bq = tid >> 4;   // phase1: b-quad index (4 b's)   [0..15]
    const int dq = mg;         // phase3: d-quad index (4 d's)
    const int bq2 = bq;        // phase3: b-quad index (4 b's)

    // stage X tile once: sX[d][b] <- XT[d][Boff+b]
    {
        const float4* src = (const float4*)XT;
        float4* dst = (float4*)sX;
        #pragma unroll
        for (int it = 0; it < 4; it++) {
            int i = it * 256 + tid;            // 0..1023
            int d = i >> 4, b4 = i & 15;
            dst[d * 16 + b4] = src[d * (B_N / 4) + (Boff >> 2) + b4];
        }
    }

    // phase-3 accumulators persist across tiles: [b][d] for K and G, + norm
    float s1a[4][4] = {{0}}, s2a[4][4] = {{0}};
    float nb[4] = {0.f, 0.f, 0.f, 0.f};

    for (int tile = 0; tile < MS / MT; tile++) {   // 2 tiles of 32 m
        int mBase = Moff + tile * MT;
        // ---- stage AP (transposed to d-major), KG (direct), q, Lam ----
        {
            const float4* srcAP = (const float4*)wsAP;   // f4 = 2 consecutive-d float2s
            const float4* srcKG = (const float4*)wsKG;
            float4* dstKG = (float4*)sKG;
            #pragma unroll
            for (int it = 0; it < 4; it++) {
                int i = it * 256 + tid;        // 0..1023
                int m = i >> 5, dp = i & 31;   // m in tile, d-pair
                float4 v = srcAP[(mBase + m) * 32 + dp];
                int d = dp * 2;
                sAP[d * 34 + m]       = make_float2(v.x, v.y);
                sAP[(d + 1) * 34 + m] = make_float2(v.z, v.w);
                dstKG[m * 32 + dp] = srcKG[(mBase + m) * 32 + dp];
            }
            if (tid < MT) sQ[tid] = qArr[mBase + tid];
            else if (tid < 2 * MT) sL[tid - MT] = Lam[mBase + tid - MT];
        }
        __syncthreads();

        // ---- phase 1: logw dot-products, thread tile 4b x 2m ----
        float acc[4][2] = {{0}};
        {
            const float4* sX4  = (const float4*)sX;
            const float4* sAP4 = (const float4*)sAP;   // row stride 17 f4
            #pragma unroll 8
            for (int d = 0; d < 64; d++) {
                float4 xv = sX4[d * 16 + bq];          // 4 b's
                float4 ap = sAP4[d * 17 + mg];         // (a0,p0,a1,p1) for m0,m0+1
                float xs[4] = {xv.x, xv.y, xv.z, xv.w};
                #pragma unroll
                for (int j = 0; j < 4; j++) {
                    float x2 = xs[j] * xs[j];
                    acc[j][0] = fmaf(x2, ap.x, fmaf(xs[j], ap.y, acc[j][0]));
                    acc[j][1] = fmaf(x2, ap.z, fmaf(xs[j], ap.w, acc[j][1]));
                }
            }
        }

        // ---- phase 2: w = exp(clip(-0.5*(dot+q))) * Lam -> sW[m][b] ----
        {
            int m0 = 2 * mg, b0 = 4 * bq;
            #pragma unroll
            for (int i = 0; i < 2; i++) {
                float q = sQ[m0 + i], lam = sL[m0 + i];
                #pragma unroll
                for (int j = 0; j < 4; j++) {
                    float lw = -0.5f * (acc[j][i] + q);
                    lw = fminf(50.f, fmaxf(-50.f, lw));
                    sW[(m0 + i) * 68 + b0 + j] = __expf(lw) * lam;
                }
            }
        }
        __syncthreads();

        // ---- phase 3: S1 += w*K, S2 += w*g, thread tile 4b x 4d ----
        {
            const float4* sKG4 = (const float4*)sKG;   // row stride 32 f4
            #pragma unroll 4
            for (int m = 0; m < MT; m++) {
                float4 wv  = *(const float4*)&sW[m * 68 + 4 * bq2];
                float4 kgA = sKG4[m * 32 + 2 * dq];     // (k0,g0,k1,g1) d0..d0+1
                float4 kgB = sKG4[m * 32 + 2 * dq + 1]; // d0+2..d0+3
                float ws4[4] = {wv.x, wv.y, wv.z, wv.w};
                #pragma unroll
                for (int j = 0; j < 4; j++) {
                    float wj = ws4[j];
                    s1a[j][0] = fmaf(wj, kgA.x, s1a[j][0]);
                    s2a[j][0] = fmaf(wj, kgA.y, s2a[j][0]);
                    s1a[j][1] = fmaf(wj, kgA.z, s1a[j][1]);
                    s2a[j][1] = fmaf(wj, kgA.w, s2a[j][1]);
                    s1a[j][2] = fmaf(wj, kgB.x, s1a[j][2]);
                    s2a[j][2] = fmaf(wj, kgB.y, s2a[j][2]);
                    s1a[j][3] = fmaf(wj, kgB.z, s1a[j][3]);
                    s2a[j][3] = fmaf(wj, kgB.w, s2a[j][3]);
                    nb[j] += wj;   // all dq threads compute same norm; dq==0 writes
                }
            }
        }
        __syncthreads();
    }

    // ---- epilogue: write partials [split][b][PROW] ----
    {
        int d0 = 4 * dq;
        #pragma unroll
        for (int j = 0; j < 4; j++) {
            int b = Boff + 4 * bq2 + j;
            float* row = part + ((size_t)blockIdx.y * B_N + b) * PROW;
            *(float4*)(row + d0)      = make_float4(s1a[j][0], s1a[j][1], s1a[j][2], s1a[j][3]);
            *(float4*)(row + 64 + d0) = make_float4(s2a[j][0], s2a[j][1], s2a[j][2], s2a[j][3]);
            if (dq == 0) row[128] = nb[j];
        }
    }
}

// ---------------- kernel 4: reduce splits, finalize ----------------
__global__ void finalize_kernel(const float* __restrict__ X, const float* __restrict__ part,
                                float* __restrict__ out) {
    int gid = blockIdx.x * 256 + threadIdx.x;   // 131072
    int b = gid >> 6, d = gid & 63;
    float a1 = 0.f, a2 = 0.f, nn = 0.f;
    #pragma unroll
    for (int s = 0; s < NSPLIT; s++) {
        const float* row = part + ((size_t)s * B_N + b) * PROW;
        a1 += row[d];
        a2 += row[64 + d];
        nn += row[128];
    }
    out[gid] = (X[gid] * a1 + a2) / nn;
}

extern "C" void kernel_launch(void* const* d_in, const int* in_sizes, int n_in,
                              void* d_out, int out_size, void* d_ws, size_t ws_size,
                              hipStream_t stream) {
    (void)in_sizes; (void)n_in; (void)out_size; (void)ws_size;
    const float* X   = (const float*)d_in[0];
    const float* Mu0 = (const float*)d_in[1];
    const float* Mu1 = (const float*)d_in[2];
    const float* S0  = (const float*)d_in[3];
    const float* S1  = (const float*)d_in[4];
    const float* Lam = (const float*)d_in[5];
    const float* T   = (const float*)d_in[6];
    const float* E   = (const float*)d_in[7];

    char* ws = (char*)d_ws;
    // ws layout: AP 512KB | KG 512KB | XT 512KB | q 4KB | partials 16*2048*132*4 = 16.5MB
    float2* wsAP = (float2*)(ws);
    float2* wsKG = (float2*)(ws + (512 << 10));
    float*  wsXT = (float*)(ws + (1 << 20));
    float*  qArr = (float*)(ws + (1 << 20) + (512 << 10));
    float*  part = (float*)(ws + (1 << 20) + (512 << 10) + 4096);

    precomp_kernel<<<256, 256, 0, stream>>>(Mu0, Mu1, S0, S1, T, E, wsAP, wsKG, qArr);
    transposeX_kernel<<<512, 256, 0, stream>>>(X, wsXT);
    dim3 grid(B_N / BT, NSPLIT);
    gmm_main_kernel<<<grid, 256, 0, stream>>>(Lam, wsAP, wsKG, wsXT, qArr, part);
    finalize_kernel<<<512, 256, 0, stream>>>(X, part, (float*)d_out);
}

// Round 2
// 98.271 us; speedup vs baseline: 1.0502x; 1.0502x over previous
//
#include <hip/hip_runtime.h>
#include <math.h>

// GMMflow_fast: B=2048 points, M=1024 components, D=64 dims.
//   logw[b,m] = -0.5*( sum_d x*(x*a + p') + q[m] ),  a=1/Sigma, p'=-2*mut*a,
//   q[m] = sum_d (mut^2*a + ln Sigma)
//   u[b,d] = ( x[b,d]*S1[b,d] + S2[b,d] ) / norm[b]
//   S1 = sum_m w*K, S2 = sum_m w*(v - K*mut), norm = sum_m w, w = exp(clip(logw))*Lam
// f32 VALU throughout (no f32 MFMA on CDNA4; exp() amplifies bf16 error).

#define B_N 2048
#define M_N 1024
#define NSPLIT 16
#define BT 64              // b-tile per block
#define MS 64              // m per block (= split size), single LDS tile
#define PROW 132           // partial row: 64 S1 + 64 S2 + norm + pad (16B-aligned)

// ---------- kernel A: precomp (blocks 0..255) + X transpose (blocks 256..287) ----------
__global__ __launch_bounds__(256)
void prep_kernel(const float* __restrict__ X,
                 const float* __restrict__ Mu0, const float* __restrict__ Mu1,
                 const float* __restrict__ S0, const float* __restrict__ S1,
                 const float* __restrict__ T, const float* __restrict__ E,
                 float2* __restrict__ wsAP, float2* __restrict__ wsKG,
                 float* __restrict__ qArr, float* __restrict__ XT) {
    __shared__ __align__(16) float sT[64 * 68];
    const int tid = threadIdx.x;
    if (blockIdx.x < 256) {
        // per-component precompute: one 64-lane wave per m, lane = d
        int gid = blockIdx.x * 256 + tid;
        int m = gid >> 6, d = gid & 63;
        float t = T[0], e = E[0];
        float eps2 = e * e, eps4 = eps2 * eps2;
        int idx = m * 64 + d;
        float s0 = S0[idx], s1 = S1[idx];
        float mu0 = Mu0[idx], mu1 = Mu1[idx];
        float Ds = sqrtf(4.f * s0 * s1 + eps4);
        float Cs = 0.5f * (Ds - eps2);
        float omt = 1.f - t;
        float sig = omt * omt * s0 + t * t * s1 + 2.f * t * omt * (Cs + 0.5f * eps2);
        float St = (t * s1 + omt * Cs) - (omt * s0 + t * Cs) - eps2 * t;
        float a = 1.f / sig;
        float K = St * a;
        float mut = omt * mu0 + t * mu1;
        wsAP[idx] = make_float2(a, -2.f * mut * a);          // (a, p')
        wsKG[idx] = make_float2(K, (mu1 - mu0) - K * mut);   // (K, g)
        float qd = mut * mut * a + logf(sig);
        #pragma unroll
        for (int off = 32; off > 0; off >>= 1) qd += __shfl_xor(qd, off, 64);
        if (d == 0) qArr[m] = qd;
    } else {
        // LDS-tiled transpose: X[b][d] -> XT[d][b], coalesced both directions
        int Boff = (blockIdx.x - 256) * 64;
        const float4* X4 = (const float4*)X;
        #pragma unroll
        for (int it = 0; it < 4; it++) {
            int i = it * 256 + tid;
            int b = i >> 4, dq = i & 15;
            float4 v = X4[(Boff + b) * 16 + dq];
            sT[(4 * dq + 0) * 68 + b] = v.x;
            sT[(4 * dq + 1) * 68 + b] = v.y;
            sT[(4 * dq + 2) * 68 + b] = v.z;
            sT[(4 * dq + 3) * 68 + b] = v.w;
        }
        __syncthreads();
        float4* XT4 = (float4*)XT;
        #pragma unroll
        for (int it = 0; it < 4; it++) {
            int i = it * 256 + tid;
            int d = i >> 4, bq = i & 15;
            XT4[d * (B_N / 4) + (Boff >> 2) + bq] = *(const float4*)&sT[d * 68 + 4 * bq];
        }
    }
}

// ---------- kernel B: fused main ----------
// grid (B/64=32, NSPLIT=16) = 512 blocks, 256 thr, 67.5 KB LDS -> 2 blocks/CU.
// thread tile: phase1 4b x 4m, phase3 4b x 4d. KG read direct from global (L2-resident).
__global__ __launch_bounds__(256, 2)
void gmm_main_kernel(const float* __restrict__ Lam,
                     const float2* __restrict__ wsAP, const float2* __restrict__ wsKG,
                     const float* __restrict__ XT, const float* __restrict__ qArr,
                     float* __restrict__ part) {
    // sX [64d][64b] f, sA [64d][68] f, sP [64d][68] f, sW [64m][68] f, sQ[64], sL[64]
    __shared__ __align__(16) float smem[17280];   // 69120 B
    float* sX = smem;            // 4096
    float* sA = smem + 4096;     // 4352
    float* sP = smem + 8448;     // 4352
    float* sW = smem + 12800;    // 4352
    float* sQ = smem + 17152;    // 64
    float* sL = smem + 17216;    // 64

    const int tid  = threadIdx.x;
    const int Boff = blockIdx.x * BT;
    const int Moff = blockIdx.y * MS;
    const int mg = tid & 15;    // phase1: m-quad [0,16); phase3: d-quad
    const int bq = tid >> 4;    // b-quad [0,16)

    // ---- stage X tile: sX[d][b] <- XT[d][Boff+b] (coalesced, conflict-free) ----
    {
        const float4* src = (const float4*)XT;
        float4* dst = (float4*)sX;
        #pragma unroll
        for (int it = 0; it < 4; it++) {
            int i = it * 256 + tid;
            int d = i >> 4, b4 = i & 15;
            dst[d * 16 + b4] = src[d * (B_N / 4) + (Boff >> 2) + b4];
        }
    }
    // ---- stage A,P split d-major (f4 reads in phase1 are 2-way bank-aliased = free) ----
    {
        const float4* srcAP = (const float4*)wsAP;   // f4 = (a,p') for d, d+1
        #pragma unroll
        for (int it = 0; it < 8; it++) {
            int i = it * 256 + tid;
            int m = i >> 5, dp = i & 31;
            float4 v = srcAP[(Moff + m) * 32 + dp];
            int d = 2 * dp;
            sA[d * 68 + m] = v.x;  sP[d * 68 + m] = v.y;
            sA[(d + 1) * 68 + m] = v.z;  sP[(d + 1) * 68 + m] = v.w;
        }
        if (tid < 64) sQ[tid] = qArr[Moff + tid];
        else if (tid < 128) sL[tid - 64] = Lam[Moff + tid - 64];
    }
    __syncthreads();

    // ---- phase 1: logw dots, 4b x 4m per thread; 3 LDS b128 reads per 32 FMA ----
    float acc[4][4];   // [b][m]
    #pragma unroll
    for (int j = 0; j < 4; j++)
        #pragma unroll
        for (int i = 0; i < 4; i++) acc[j][i] = 0.f;
    {
        const float4* sX4 = (const float4*)sX;
        #pragma unroll 4
        for (int d = 0; d < 64; d++) {
            float4 xv = sX4[d * 16 + bq];
            float4 a4 = *(const float4*)&sA[d * 68 + 4 * mg];
            float4 p4 = *(const float4*)&sP[d * 68 + 4 * mg];
            float xs[4] = {xv.x, xv.y, xv.z, xv.w};
            float as[4] = {a4.x, a4.y, a4.z, a4.w};
            float ps[4] = {p4.x, p4.y, p4.z, p4.w};
            #pragma unroll
            for (int j = 0; j < 4; j++) {
                float xj = xs[j];
                #pragma unroll
                for (int i = 0; i < 4; i++)
                    acc[j][i] = fmaf(xj, fmaf(xj, as[i], ps[i]), acc[j][i]);
            }
        }
    }

    // ---- phase 2: w = exp(clip(-0.5*(dot+q))) * Lam -> sW[m][b] ----
    {
        #pragma unroll
        for (int i = 0; i < 4; i++) {
            int m = 4 * mg + i;
            float q = sQ[m], lam = sL[m];
            float4 wv;
            float lw0 = fminf(50.f, fmaxf(-50.f, -0.5f * (acc[0][i] + q)));
            float lw1 = fminf(50.f, fmaxf(-50.f, -0.5f * (acc[1][i] + q)));
            float lw2 = fminf(50.f, fmaxf(-50.f, -0.5f * (acc[2][i] + q)));
            float lw3 = fminf(50.f, fmaxf(-50.f, -0.5f * (acc[3][i] + q)));
            wv.x = __expf(lw0) * lam;
            wv.y = __expf(lw1) * lam;
            wv.z = __expf(lw2) * lam;
            wv.w = __expf(lw3) * lam;
            *(float4*)&sW[m * 68 + 4 * bq] = wv;
        }
    }
    __syncthreads();

    // ---- phase 3: S1 += w*K, S2 += w*g; w from LDS, K/G direct from global (L2) ----
    float s1a[4][4], s2a[4][4], nb[4];   // [b][d]
    #pragma unroll
    for (int j = 0; j < 4; j++) {
        nb[j] = 0.f;
        #pragma unroll
        for (int k = 0; k < 4; k++) { s1a[j][k] = 0.f; s2a[j][k] = 0.f; }
    }
    {
        const float4* KG4 = (const float4*)wsKG;   // f4 = (K,g) for d, d+1
        #pragma unroll 4
        for (int m = 0; m < MS; m++) {
            float4 wv  = *(const float4*)&sW[m * 68 + 4 * bq];
            float4 kgA = KG4[(Moff + m) * 32 + 2 * mg];      // d0, d0+1
            float4 kgB = KG4[(Moff + m) * 32 + 2 * mg + 1];  // d0+2, d0+3
            float ws4[4] = {wv.x, wv.y, wv.z, wv.w};
            #pragma unroll
            for (int j = 0; j < 4; j++) {
                float wj = ws4[j];
                s1a[j][0] = fmaf(wj, kgA.x, s1a[j][0]);
                s2a[j][0] = fmaf(wj, kgA.y, s2a[j][0]);
                s1a[j][1] = fmaf(wj, kgA.z, s1a[j][1]);
                s2a[j][1] = fmaf(wj, kgA.w, s2a[j][1]);
                s1a[j][2] = fmaf(wj, kgB.x, s1a[j][2]);
                s2a[j][2] = fmaf(wj, kgB.y, s2a[j][2]);
                s1a[j][3] = fmaf(wj, kgB.z, s1a[j][3]);
                s2a[j][3] = fmaf(wj, kgB.w, s2a[j][3]);
                nb[j] += wj;
            }
        }
    }

    // ---- epilogue: partials [split][b][PROW] ----
    {
        int d0 = 4 * mg;
        #pragma unroll
        for (int j = 0; j < 4; j++) {
            int b = Boff + 4 * bq + j;
            float* row = part + ((size_t)blockIdx.y * B_N + b) * PROW;
            *(float4*)(row + d0)      = make_float4(s1a[j][0], s1a[j][1], s1a[j][2], s1a[j][3]);
            *(float4*)(row + 64 + d0) = make_float4(s2a[j][0], s2a[j][1], s2a[j][2], s2a[j][3]);
            if (mg == 0) row[128] = nb[j];
        }
    }
}

// ---------- kernel C: reduce splits, finalize ----------
__global__ __launch_bounds__(256)
void finalize_kernel(const float* __restrict__ X, const float* __restrict__ part,
                     float* __restrict__ out) {
    int gid = blockIdx.x * 256 + threadIdx.x;   // 131072
    int b = gid >> 6, d = gid & 63;
    float a1 = 0.f, a2 = 0.f, nn = 0.f;
    #pragma unroll
    for (int s = 0; s < NSPLIT; s++) {
        const float* row = part + ((size_t)s * B_N + b) * PROW;
        a1 += row[d];
        a2 += row[64 + d];
        nn += row[128];
    }
    out[gid] = (X[gid] * a1 + a2) / nn;
}

extern "C" void kernel_launch(void* const* d_in, const int* in_sizes, int n_in,
                              void* d_out, int out_size, void* d_ws, size_t ws_size,
                              hipStream_t stream) {
    (void)in_sizes; (void)n_in; (void)out_size; (void)ws_size;
    const float* X   = (const float*)d_in[0];
    const float* Mu0 = (const float*)d_in[1];
    const float* Mu1 = (const float*)d_in[2];
    const float* S0  = (const float*)d_in[3];
    const float* S1  = (const float*)d_in[4];
    const float* Lam = (const float*)d_in[5];
    const float* T   = (const float*)d_in[6];
    const float* E   = (const float*)d_in[7];

    char* ws = (char*)d_ws;
    // ws: AP 512KB | KG 512KB | XT 512KB | q 4KB | partials 16*2048*132*4 = 16.5MB
    float2* wsAP = (float2*)(ws);
    float2* wsKG = (float2*)(ws + (512 << 10));
    float*  wsXT = (float*)(ws + (1 << 20));
    float*  qArr = (float*)(ws + (1 << 20) + (512 << 10));
    float*  part = (float*)(ws + (1 << 20) + (512 << 10) + 4096);

    prep_kernel<<<288, 256, 0, stream>>>(X, Mu0, Mu1, S0, S1, T, E, wsAP, wsKG, qArr, wsXT);
    dim3 grid(B_N / BT, NSPLIT);
    gmm_main_kernel<<<grid, 256, 0, stream>>>(Lam, wsAP, wsKG, wsXT, qArr, part);
    finalize_kernel<<<512, 256, 0, stream>>>(X, part, (float*)d_out);
}

// Round 3
// 98.159 us; speedup vs baseline: 1.0514x; 1.0011x over previous
//
#include <hip/hip_runtime.h>
#include <math.h>

// GMMflow_fast: B=2048, M=1024, D=64.
//   logw[b,m] = -0.5*( sum_d x*(x*a + p') + q[m] ),  a=1/Sigma, p'=-2*mut*a
//   u[b,d] = ( x[b,d]*S1[b,d] + S2[b,d] ) / norm[b]
//   S1 = sum_m w*K, S2 = sum_m w*g, norm = sum_m w, w = exp(clip(logw))*Lam
// f32 VALU throughout (no f32 MFMA on CDNA4; exp() amplifies bf16 error).
//
// R3: BT=128 b-tile, 8b x 4m phase-1 thread tile (4 LDS b128 per 64 FMA vs 3/32),
// KG staged to LDS via buffer overlay (sKG over dead sX, sW over dead sA/sP).
// grid (16,16)=256 blocks, 1 block/CU, LDS 68.1 KB.

#define B_N 2048
#define M_N 1024
#define NSPLIT 16
#define BT 128             // b per block
#define MS 64              // m per block (= M/NSPLIT), single tile
#define PROW 132           // partial row: 64 S1 + 64 S2 + norm + pad

// ---------- kernel A: precomp (blocks 0..255) + X transpose (blocks 256..287) ----------
__global__ __launch_bounds__(256)
void prep_kernel(const float* __restrict__ X,
                 const float* __restrict__ Mu0, const float* __restrict__ Mu1,
                 const float* __restrict__ S0, const float* __restrict__ S1,
                 const float* __restrict__ T, const float* __restrict__ E,
                 float2* __restrict__ wsAP, float2* __restrict__ wsKG,
                 float* __restrict__ qArr, float* __restrict__ XT) {
    __shared__ __align__(16) float sT[64 * 68];
    const int tid = threadIdx.x;
    if (blockIdx.x < 256) {
        int gid = blockIdx.x * 256 + tid;
        int m = gid >> 6, d = gid & 63;
        float t = T[0], e = E[0];
        float eps2 = e * e, eps4 = eps2 * eps2;
        int idx = m * 64 + d;
        float s0 = S0[idx], s1 = S1[idx];
        float mu0 = Mu0[idx], mu1 = Mu1[idx];
        float Ds = sqrtf(4.f * s0 * s1 + eps4);
        float Cs = 0.5f * (Ds - eps2);
        float omt = 1.f - t;
        float sig = omt * omt * s0 + t * t * s1 + 2.f * t * omt * (Cs + 0.5f * eps2);
        float St = (t * s1 + omt * Cs) - (omt * s0 + t * Cs) - eps2 * t;
        float a = 1.f / sig;
        float K = St * a;
        float mut = omt * mu0 + t * mu1;
        wsAP[idx] = make_float2(a, -2.f * mut * a);          // (a, p')
        wsKG[idx] = make_float2(K, (mu1 - mu0) - K * mut);   // (K, g)
        float qd = mut * mut * a + logf(sig);
        #pragma unroll
        for (int off = 32; off > 0; off >>= 1) qd += __shfl_xor(qd, off, 64);
        if (d == 0) qArr[m] = qd;
    } else {
        // LDS-tiled transpose X[b][d] -> XT[d][b]
        int Boff = (blockIdx.x - 256) * 64;
        const float4* X4 = (const float4*)X;
        #pragma unroll
        for (int it = 0; it < 4; it++) {
            int i = it * 256 + tid;
            int b = i >> 4, dq = i & 15;
            float4 v = X4[(Boff + b) * 16 + dq];
            sT[(4 * dq + 0) * 68 + b] = v.x;
            sT[(4 * dq + 1) * 68 + b] = v.y;
            sT[(4 * dq + 2) * 68 + b] = v.z;
            sT[(4 * dq + 3) * 68 + b] = v.w;
        }
        __syncthreads();
        float4* XT4 = (float4*)XT;
        #pragma unroll
        for (int it = 0; it < 4; it++) {
            int i = it * 256 + tid;
            int d = i >> 4, bq = i & 15;
            XT4[d * (B_N / 4) + (Boff >> 2) + bq] = *(const float4*)&sT[d * 68 + 4 * bq];
        }
    }
}

// ---------- kernel B: fused main ----------
// grid (16,16) = 256 blocks, 256 thr, 68.1 KB LDS, 1 block/CU.
// phase1 tile 8b x 4m; phase3 tile 8b x 4d; KG via LDS overlay.
__global__ __launch_bounds__(256, 1)
void gmm_main_kernel(const float* __restrict__ Lam,
                     const float2* __restrict__ wsAP, const float2* __restrict__ wsKG,
                     const float* __restrict__ XT, const float* __restrict__ qArr,
                     float* __restrict__ part) {
    // region1 [0..8191]:   sX [64 d][128 b]   ->  sKG [64 m][32 f4] after phase 1
    // region2 [8192..16895]: sA[64][68]+sP[64][68] -> sW [64 m][132] after phase 1
    __shared__ __align__(16) float smem[17024];
    float* sX  = smem;               // 8192 f
    float* sA  = smem + 8192;        // 4352 f
    float* sP  = smem + 12544;       // 4352 f
    float* sKG = smem;               // overlay on sX (8192 f)
    float* sW  = smem + 8192;        // overlay on sA+sP (8448 of 8704 f)
    float* sQ  = smem + 16896;       // 64
    float* sL  = smem + 16960;       // 64

    const int tid  = threadIdx.x;
    const int Boff = blockIdx.x * BT;
    const int Moff = blockIdx.y * MS;
    const int bg = tid >> 4;    // [0,16): 8 b's per thread
    const int mg = tid & 15;    // phase1: 4 m's; phase3: 4 d's

    // ---- stage sX[d][b] <- XT[d][Boff+b] ----
    {
        const float4* XT4 = (const float4*)XT;
        float4* dst = (float4*)sX;
        #pragma unroll
        for (int it = 0; it < 8; it++) {
            int i = it * 256 + tid;
            int d = i >> 5, q = i & 31;
            dst[d * 32 + q] = XT4[d * (B_N / 4) + (Boff >> 2) + q];
        }
    }
    // ---- stage sA, sP (d-major) ----
    {
        const float4* srcAP = (const float4*)wsAP;   // f4 = (a,p') for d, d+1
        #pragma unroll
        for (int it = 0; it < 8; it++) {
            int i = it * 256 + tid;
            int m = i >> 5, dp = i & 31;
            float4 v = srcAP[(Moff + m) * 32 + dp];
            int d = 2 * dp;
            sA[d * 68 + m] = v.x;  sP[d * 68 + m] = v.y;
            sA[(d + 1) * 68 + m] = v.z;  sP[(d + 1) * 68 + m] = v.w;
        }
        if (tid < 64) sQ[tid] = qArr[Moff + tid];
        else if (tid < 128) sL[tid - 64] = Lam[Moff + tid - 64];
    }
    __syncthreads();

    // ---- phase 1: logw dots, 8b x 4m; 4 LDS b128 per 64 FMA ----
    float acc[8][4];
    #pragma unroll
    for (int j = 0; j < 8; j++)
        #pragma unroll
        for (int i = 0; i < 4; i++) acc[j][i] = 0.f;
    {
        const float4* sX4 = (const float4*)sX;   // row stride 32 f4
        const float4* sA4 = (const float4*)sA;   // row stride 17 f4
        const float4* sP4 = (const float4*)sP;
        #pragma unroll 4
        for (int d = 0; d < 64; d++) {
            float4 xA = sX4[d * 32 + 2 * bg];
            float4 xB = sX4[d * 32 + 2 * bg + 1];
            float4 a4 = sA4[d * 17 + mg];
            float4 p4 = sP4[d * 17 + mg];
            float xs[8] = {xA.x, xA.y, xA.z, xA.w, xB.x, xB.y, xB.z, xB.w};
            float as[4] = {a4.x, a4.y, a4.z, a4.w};
            float ps[4] = {p4.x, p4.y, p4.z, p4.w};
            #pragma unroll
            for (int j = 0; j < 8; j++) {
                float xj = xs[j];
                #pragma unroll
                for (int i = 0; i < 4; i++)
                    acc[j][i] = fmaf(xj, fmaf(xj, as[i], ps[i]), acc[j][i]);
            }
        }
    }
    __syncthreads();   // region1/region2 reads done; safe to overlay

    // ---- phase 2: stage sKG (overlay sX) + w = exp(...)*Lam -> sW (overlay sA/sP) ----
    {
        const float4* KG4 = (const float4*)wsKG;
        float4* sKG4 = (float4*)sKG;
        float4 tmp[8];
        #pragma unroll
        for (int it = 0; it < 8; it++) {
            int i = it * 256 + tid;
            tmp[it] = KG4[(size_t)(Moff + (i >> 5)) * 32 + (i & 31)];
        }
        #pragma unroll
        for (int i = 0; i < 4; i++) {
            int m = 4 * mg + i;
            float q = sQ[m], lam = sL[m];
            float w[8];
            #pragma unroll
            for (int j = 0; j < 8; j++) {
                float lw = fminf(50.f, fmaxf(-50.f, -0.5f * (acc[j][i] + q)));
                w[j] = __expf(lw) * lam;
            }
            *(float4*)&sW[m * 132 + 8 * bg]     = make_float4(w[0], w[1], w[2], w[3]);
            *(float4*)&sW[m * 132 + 8 * bg + 4] = make_float4(w[4], w[5], w[6], w[7]);
        }
        #pragma unroll
        for (int it = 0; it < 8; it++) {
            int i = it * 256 + tid;
            sKG4[(i >> 5) * 32 + (i & 31)] = tmp[it];
        }
    }
    __syncthreads();

    // ---- phase 3: S1 += w*K, S2 += w*g; 8b x 4d, all LDS ----
    float s1a[8][4], s2a[8][4], nb[8];
    #pragma unroll
    for (int j = 0; j < 8; j++) {
        nb[j] = 0.f;
        #pragma unroll
        for (int k = 0; k < 4; k++) { s1a[j][k] = 0.f; s2a[j][k] = 0.f; }
    }
    {
        const float4* sKG4 = (const float4*)sKG;   // row stride 32 f4
        #pragma unroll 4
        for (int m = 0; m < MS; m++) {
            float4 wv1 = *(const float4*)&sW[m * 132 + 8 * bg];
            float4 wv2 = *(const float4*)&sW[m * 132 + 8 * bg + 4];
            float4 kgA = sKG4[m * 32 + 2 * mg];      // (K,g) d0, d0+1
            float4 kgB = sKG4[m * 32 + 2 * mg + 1];  // d0+2, d0+3
            float ws8[8] = {wv1.x, wv1.y, wv1.z, wv1.w, wv2.x, wv2.y, wv2.z, wv2.w};
            #pragma unroll
            for (int j = 0; j < 8; j++) {
                float wj = ws8[j];
                s1a[j][0] = fmaf(wj, kgA.x, s1a[j][0]);
                s2a[j][0] = fmaf(wj, kgA.y, s2a[j][0]);
                s1a[j][1] = fmaf(wj, kgA.z, s1a[j][1]);
                s2a[j][1] = fmaf(wj, kgA.w, s2a[j][1]);
                s1a[j][2] = fmaf(wj, kgB.x, s1a[j][2]);
                s2a[j][2] = fmaf(wj, kgB.y, s2a[j][2]);
                s1a[j][3] = fmaf(wj, kgB.z, s1a[j][3]);
                s2a[j][3] = fmaf(wj, kgB.w, s2a[j][3]);
                nb[j] += wj;
            }
        }
    }

    // ---- epilogue: partials [split][b][PROW] ----
    {
        int d0 = 4 * mg;
        #pragma unroll
        for (int j = 0; j < 8; j++) {
            int b = Boff + 8 * bg + j;
            float* row = part + ((size_t)blockIdx.y * B_N + b) * PROW;
            *(float4*)(row + d0)      = make_float4(s1a[j][0], s1a[j][1], s1a[j][2], s1a[j][3]);
            *(float4*)(row + 64 + d0) = make_float4(s2a[j][0], s2a[j][1], s2a[j][2], s2a[j][3]);
            if (mg == 0) row[128] = nb[j];
        }
    }
}

// ---------- kernel C: reduce splits, finalize ----------
__global__ __launch_bounds__(256)
void finalize_kernel(const float* __restrict__ X, const float* __restrict__ part,
                     float* __restrict__ out) {
    int gid = blockIdx.x * 256 + threadIdx.x;   // 131072
    int b = gid >> 6, d = gid & 63;
    float a1 = 0.f, a2 = 0.f, nn = 0.f;
    #pragma unroll
    for (int s = 0; s < NSPLIT; s++) {
        const float* row = part + ((size_t)s * B_N + b) * PROW;
        a1 += row[d];
        a2 += row[64 + d];
        nn += row[128];
    }
    out[gid] = (X[gid] * a1 + a2) / nn;
}

extern "C" void kernel_launch(void* const* d_in, const int* in_sizes, int n_in,
                              void* d_out, int out_size, void* d_ws, size_t ws_size,
                              hipStream_t stream) {
    (void)in_sizes; (void)n_in; (void)out_size; (void)ws_size;
    const float* X   = (const float*)d_in[0];
    const float* Mu0 = (const float*)d_in[1];
    const float* Mu1 = (const float*)d_in[2];
    const float* S0  = (const float*)d_in[3];
    const float* S1  = (const float*)d_in[4];
    const float* Lam = (const float*)d_in[5];
    const float* T   = (const float*)d_in[6];
    const float* E   = (const float*)d_in[7];

    char* ws = (char*)d_ws;
    // ws: AP 512KB | KG 512KB | XT 512KB | q 4KB | partials 16*2048*132*4 = 16.9MB
    float2* wsAP = (float2*)(ws);
    float2* wsKG = (float2*)(ws + (512 << 10));
    float*  wsXT = (float*)(ws + (1 << 20));
    float*  qArr = (float*)(ws + (1 << 20) + (512 << 10));
    float*  part = (float*)(ws + (1 << 20) + (512 << 10) + 4096);

    prep_kernel<<<288, 256, 0, stream>>>(X, Mu0, Mu1, S0, S1, T, E, wsAP, wsKG, qArr, wsXT);
    dim3 grid(B_N / BT, NSPLIT);
    gmm_main_kernel<<<grid, 256, 0, stream>>>(Lam, wsAP, wsKG, wsXT, qArr, part);
    finalize_kernel<<<512, 256, 0, stream>>>(X, part, (float*)d_out);
}